// Round 1
// baseline (735.586 us; speedup 1.0000x reference)
//
#include <hip/hip_runtime.h>
#include <hip/hip_bf16.h>

typedef float f32x4 __attribute__((ext_vector_type(4)));
typedef __bf16 bf16x8 __attribute__((ext_vector_type(8)));
typedef unsigned short u16x8 __attribute__((ext_vector_type(8)));

#define GN_EPS 1e-5f
#define LN_EPS 1e-5f
#define COS_EPS_F 1e-8f

__device__ __forceinline__ unsigned short f2bf(float f) {
  unsigned int u = __builtin_bit_cast(unsigned int, f);
  u += 0x7fffu + ((u >> 16) & 1u);   // round-to-nearest-even
  return (unsigned short)(u >> 16);
}

// ---------------------------------------------------------------------------
// Pad + transpose + bf16 cast: x[b][ci][16][16] f32 -> xp[b][18][18][256] bf16
// block = one (b, sh); thread = ci; sw loop keeps each thread on one 64B line
// ---------------------------------------------------------------------------
__global__ void pad_kernel(const float* __restrict__ x, unsigned short* __restrict__ xp) {
  int bs = blockIdx.x;            // b*18 + sh
  int sh = bs % 18, b = bs / 18;
  int ci = threadIdx.x;           // 0..255
  int h = sh - 1;
  const float* xr = x + (((b * 256 + ci) * 16 + h) * 16);  // valid only if h in range
  unsigned short* op = xp + bs * 18 * 256 + ci;
  bool hok = (h >= 0) && (h < 16);
  #pragma unroll
  for (int sw = 0; sw < 18; ++sw) {
    int w = sw - 1;
    float v = 0.f;
    if (hok && w >= 0 && w < 16) v = xr[w];
    op[sw * 256] = f2bf(v);
  }
}

// ---------------------------------------------------------------------------
// Repack conv weight: W[co][ci][3][3] f32 -> wp[co][9][ci] bf16 (B^T layout)
// ---------------------------------------------------------------------------
__global__ void pack_kernel(const float* __restrict__ w, unsigned short* __restrict__ wp) {
  int idx = blockIdx.x * 256 + threadIdx.x;   // 0..589823
  int ci = idx & 255;
  int rest = idx >> 8;
  int khw = rest % 9, co = rest / 9;
  wp[idx] = f2bf(w[(co * 256 + ci) * 9 + khw]);
}

// ---------------------------------------------------------------------------
// Fused Conv3x3 (implicit GEMM, bf16 MFMA) + bias + GroupNorm(16) + ReLU +
// spatial mean. Block = (b, nt): 256 spatial rows x 128 channels, 8 waves.
// ---------------------------------------------------------------------------
__device__ __forceinline__ void gl_lds16(const unsigned short* g, unsigned short* l) {
  __builtin_amdgcn_global_load_lds(
      (const __attribute__((address_space(1))) void*)g,
      (__attribute__((address_space(3))) void*)l, 16, 0, 0);
}

__launch_bounds__(512, 2)
__global__ void conv_gn_pool(const unsigned short* __restrict__ xp,
                             const unsigned short* __restrict__ wp,
                             const float* __restrict__ cbias,
                             const float* __restrict__ gng,
                             const float* __restrict__ gnb,
                             float* __restrict__ enc) {
  __shared__ unsigned short At[256 * 64];   // 32 KB  [row][k] (k-chunks XOR-swizzled by row&7)
  __shared__ unsigned short Bt[128 * 64];   // 16 KB  [co][k]
  __shared__ float gsum[8], gsq[8], pooled[128];

  int bid = blockIdx.x;                     // 0..511
  int swz = (bid & 7) * 64 + (bid >> 3);    // XCD swizzle: both halves of image b on same XCD
  int b = swz >> 1, nt = swz & 1;
  int tid = threadIdx.x;
  int wid = tid >> 6, lane = tid & 63;
  int wr = wid >> 1, wc = wid & 1;          // wave grid 4(M) x 2(N), wave tile 64x64
  int l15 = lane & 15, l4 = lane >> 4;

  if (tid < 8) { gsum[tid] = 0.f; gsq[tid] = 0.f; }
  if (tid < 128) pooled[tid] = 0.f;

  f32x4 acc[4][4];
  #pragma unroll
  for (int i = 0; i < 4; ++i)
    #pragma unroll
    for (int j = 0; j < 4; ++j) acc[i][j] = (f32x4)(0.0f);

  const unsigned short* xb = xp + b * (18 * 18 * 256);

  for (int kh = 0; kh < 3; ++kh) {
    for (int kw = 0; kw < 3; ++kw) {
      int khw = kh * 3 + kw;
      for (int ci0 = 0; ci0 < 256; ci0 += 64) {
        // ---- stage A: 256 rows x 64 k (2048 16B-chunks, 4/thread) ----
        #pragma unroll
        for (int it = 0; it < 4; ++it) {
          int s = it * 512 + tid;
          int r = s >> 3, c = s & 7;
          int cs = c ^ (r & 7);            // pre-swizzle the SOURCE chunk (rule 21)
          const unsigned short* src =
              xb + (((r >> 4) + kh) * 18 + (r & 15) + kw) * 256 + ci0 + cs * 8;
          gl_lds16(src, &At[s * 8]);
        }
        // ---- stage B: 128 co x 64 k (1024 chunks, 2/thread) ----
        #pragma unroll
        for (int it = 0; it < 2; ++it) {
          int s = it * 512 + tid;
          int co = s >> 3, c = s & 7;
          int cs = c ^ (co & 7);
          const unsigned short* src =
              wp + ((nt * 128 + co) * 9 + khw) * 256 + ci0 + cs * 8;
          gl_lds16(src, &Bt[s * 8]);
        }
        __syncthreads();                   // compiler drains vmcnt here
        #pragma unroll
        for (int ksub = 0; ksub < 2; ++ksub) {
          int kk = ksub * 32 + l4 * 8;
          bf16x8 af[4], bf[4];
          #pragma unroll
          for (int mf = 0; mf < 4; ++mf) {
            int row = wr * 64 + mf * 16 + l15;
            af[mf] = __builtin_bit_cast(
                bf16x8, *(const u16x8*)&At[row * 64 + (kk ^ ((row & 7) << 3))]);
          }
          #pragma unroll
          for (int nf = 0; nf < 4; ++nf) {
            int co = wc * 64 + nf * 16 + l15;
            bf[nf] = __builtin_bit_cast(
                bf16x8, *(const u16x8*)&Bt[co * 64 + (kk ^ ((co & 7) << 3))]);
          }
          #pragma unroll
          for (int mf = 0; mf < 4; ++mf)
            #pragma unroll
            for (int nf = 0; nf < 4; ++nf)
              acc[mf][nf] = __builtin_amdgcn_mfma_f32_16x16x32_bf16(
                  af[mf], bf[nf], acc[mf][nf], 0, 0, 0);
        }
        __syncthreads();
      }
    }
  }

  // ---- epilogue: +bias, group stats (8 groups fully inside this block) ----
  float bias[4], gg[4], gb[4];
  #pragma unroll
  for (int nf = 0; nf < 4; ++nf) {
    int co = nt * 128 + wc * 64 + nf * 16 + l15;
    bias[nf] = cbias[co]; gg[nf] = gng[co]; gb[nf] = gnb[co];
  }
  #pragma unroll
  for (int nf = 0; nf < 4; ++nf) {
    float s1 = 0.f, s2 = 0.f;
    #pragma unroll
    for (int mf = 0; mf < 4; ++mf)
      #pragma unroll
      for (int i = 0; i < 4; ++i) {
        float v = acc[mf][nf][i] + bias[nf];
        acc[mf][nf][i] = v;
        s1 += v; s2 += v * v;
      }
    #pragma unroll
    for (int d = 1; d < 64; d <<= 1) {
      s1 += __shfl_xor(s1, d);
      s2 += __shfl_xor(s2, d);
    }
    if (lane == 0) {
      atomicAdd(&gsum[wc * 4 + nf], s1);
      atomicAdd(&gsq[wc * 4 + nf], s2);
    }
  }
  __syncthreads();
  // ---- normalize + relu + pool ----
  #pragma unroll
  for (int nf = 0; nf < 4; ++nf) {
    int g = wc * 4 + nf;
    float mean = gsum[g] * (1.f / 4096.f);
    float var = gsq[g] * (1.f / 4096.f) - mean * mean;
    float rs = rsqrtf(var + GN_EPS);
    float p = 0.f;
    #pragma unroll
    for (int mf = 0; mf < 4; ++mf)
      #pragma unroll
      for (int i = 0; i < 4; ++i) {
        float v = (acc[mf][nf][i] - mean) * rs * gg[nf] + gb[nf];
        p += fmaxf(v, 0.f);
      }
    p += __shfl_xor(p, 16);
    p += __shfl_xor(p, 32);
    if (lane < 16) atomicAdd(&pooled[wc * 64 + nf * 16 + l15], p);
  }
  __syncthreads();
  if (tid < 128)
    enc[b * 256 + nt * 128 + tid] = pooled[tid] * (1.f / 256.f);
}

// ---------------------------------------------------------------------------
// Projector + LN + l2norm + predictor. One block per row (768 rows).
// ---------------------------------------------------------------------------
__global__ void proj_pred(const float* __restrict__ enc,
                          const float* __restrict__ w1, const float* __restrict__ b1,
                          const float* __restrict__ w2, const float* __restrict__ b2,
                          const float* __restrict__ lng, const float* __restrict__ lnb,
                          const float* __restrict__ pw1, const float* __restrict__ pb1,
                          const float* __restrict__ pw2, const float* __restrict__ pb2,
                          float* __restrict__ proj, float* __restrict__ pred,
                          float* __restrict__ znorm) {
  __shared__ float row[256], h1[256], zz[128], p1[128], red[2];
  int r = blockIdx.x, tid = threadIdx.x;
  row[tid] = enc[r * 256 + tid];
  __syncthreads();
  float a = 0.f;
  for (int k = 0; k < 256; ++k) a += row[k] * w1[k * 256 + tid];
  h1[tid] = fmaxf(a + b1[tid], 0.f);
  __syncthreads();
  if (tid < 128) {
    a = 0.f;
    for (int k = 0; k < 256; ++k) a += h1[k] * w2[k * 128 + tid];
    zz[tid] = a + b2[tid];
  }
  __syncthreads();
  if (tid == 0) {
    float m = 0.f;
    for (int k = 0; k < 128; ++k) m += zz[k];
    m *= (1.f / 128.f);
    float v = 0.f;
    for (int k = 0; k < 128; ++k) { float d = zz[k] - m; v += d * d; }
    red[0] = m;
    red[1] = rsqrtf(v * (1.f / 128.f) + LN_EPS);
  }
  __syncthreads();
  float zval = 0.f;
  if (tid < 128) {
    zval = (zz[tid] - red[0]) * red[1] * lng[tid] + lnb[tid];
    proj[r * 128 + tid] = zval;
  }
  __syncthreads();
  if (tid < 128) zz[tid] = zval;     // zz now holds LN output
  __syncthreads();
  if (tid == 0) {
    float s = 0.f;
    for (int k = 0; k < 128; ++k) s += zz[k] * zz[k];
    red[0] = 1.f / fmaxf(sqrtf(s), COS_EPS_F);
  }
  __syncthreads();
  if (tid < 128) {
    znorm[r * 128 + tid] = zz[tid] * red[0];
    a = 0.f;
    for (int k = 0; k < 128; ++k) a += zz[k] * pw1[k * 128 + tid];
    p1[tid] = fmaxf(a + pb1[tid], 0.f);
  }
  __syncthreads();
  if (tid < 128) {
    a = 0.f;
    for (int k = 0; k < 128; ++k) a += p1[k] * pw2[k * 128 + tid];
    pred[r * 128 + tid] = a + pb2[tid];
  }
}

// ---------------------------------------------------------------------------
// Loss: block = (pair, k). lse(S[k,:]) - S[k,k] per row; partials to ws.
// ---------------------------------------------------------------------------
__global__ void loss_kernel(const float* __restrict__ zn, float* __restrict__ part) {
  __shared__ float zi[128], sv[256], rbuf[256];
  int blk = blockIdx.x;           // p*256 + k
  int p = blk >> 8, k = blk & 255;
  int i = (p == 2) ? 1 : 0;
  int j = (p == 0) ? 1 : 2;
  int tid = threadIdx.x;
  if (tid < 128) zi[tid] = zn[(i * 256 + k) * 128 + tid];
  __syncthreads();
  const float4* zj = (const float4*)&zn[(j * 256 + tid) * 128];
  float s = 0.f;
  #pragma unroll 8
  for (int d = 0; d < 32; ++d) {
    float4 aq = *(const float4*)&zi[d * 4];
    float4 bq = zj[d];
    s += aq.x * bq.x + aq.y * bq.y + aq.z * bq.z + aq.w * bq.w;
  }
  s *= 10.0f;                      // 1/TEMP
  sv[tid] = s;
  rbuf[tid] = s;
  __syncthreads();
  for (int d = 128; d > 0; d >>= 1) {
    if (tid < d) rbuf[tid] = fmaxf(rbuf[tid], rbuf[tid + d]);
    __syncthreads();
  }
  float m = rbuf[0];
  __syncthreads();
  rbuf[tid] = expf(s - m);
  __syncthreads();
  for (int d = 128; d > 0; d >>= 1) {
    if (tid < d) rbuf[tid] += rbuf[tid + d];
    __syncthreads();
  }
  if (tid == 0) part[blk] = m + logf(rbuf[0]) - sv[k];
}

__global__ void finalize_loss(const float* __restrict__ part, float* __restrict__ out) {
  __shared__ float red[256];
  int tid = threadIdx.x;
  float s = 0.f;
  for (int idx = tid; idx < 768; idx += 256) s += part[idx];
  red[tid] = s;
  __syncthreads();
  for (int d = 128; d > 0; d >>= 1) {
    if (tid < d) red[tid] += red[tid + d];
    __syncthreads();
  }
  if (tid == 0) out[0] = red[0] * (1.f / 768.f);
}

// ---------------------------------------------------------------------------
extern "C" void kernel_launch(void* const* d_in, const int* in_sizes, int n_in,
                              void* d_out, int out_size, void* d_ws, size_t ws_size,
                              hipStream_t stream) {
  const float* x[3]  = {(const float*)d_in[0], (const float*)d_in[1], (const float*)d_in[2]};
  const float* cw[3] = {(const float*)d_in[3], (const float*)d_in[7], (const float*)d_in[11]};
  const float* cb[3] = {(const float*)d_in[4], (const float*)d_in[8], (const float*)d_in[12]};
  const float* gg[3] = {(const float*)d_in[5], (const float*)d_in[9], (const float*)d_in[13]};
  const float* gb[3] = {(const float*)d_in[6], (const float*)d_in[10], (const float*)d_in[14]};
  const float* p_w1 = (const float*)d_in[15];
  const float* p_b1 = (const float*)d_in[16];
  const float* p_w2 = (const float*)d_in[17];
  const float* p_b2 = (const float*)d_in[18];
  const float* ln_g = (const float*)d_in[19];
  const float* ln_b = (const float*)d_in[20];
  const float* q_w1 = (const float*)d_in[21];
  const float* q_b1 = (const float*)d_in[22];
  const float* q_w2 = (const float*)d_in[23];
  const float* q_b2 = (const float*)d_in[24];

  float* out = (float*)d_out;
  char* ws = (char*)d_ws;
  unsigned short* xpad = (unsigned short*)ws;                 // 42,467,328 B
  unsigned short* wpk  = (unsigned short*)(ws + 42467328);    //  1,179,648 B
  float* znorm = (float*)(ws + 43646976);                     //    393,216 B
  float* part  = (float*)(ws + 44040192);                     //      3,072 B

  float* enc  = out;              // [3][256][256]
  float* proj = out + 196608;     // [3][256][128]
  float* pred = out + 294912;     // [3][256][128]
  float* lossp = out + 393216;    // scalar

  for (int m = 0; m < 3; ++m) {
    pad_kernel<<<dim3(256 * 18), dim3(256), 0, stream>>>(x[m], xpad);
    pack_kernel<<<dim3(2304), dim3(256), 0, stream>>>(cw[m], wpk);
    conv_gn_pool<<<dim3(512), dim3(512), 0, stream>>>(xpad, wpk, cb[m], gg[m], gb[m],
                                                      enc + m * 65536);
  }
  proj_pred<<<dim3(768), dim3(256), 0, stream>>>(enc, p_w1, p_b1, p_w2, p_b2, ln_g, ln_b,
                                                 q_w1, q_b1, q_w2, q_b2, proj, pred, znorm);
  loss_kernel<<<dim3(768), dim3(256), 0, stream>>>(znorm, part);
  finalize_loss<<<dim3(1), dim3(256), 0, stream>>>(part, lossp);
}

// Round 2
// 389.914 us; speedup vs baseline: 1.8865x; 1.8865x over previous
//
#include <hip/hip_runtime.h>
#include <hip/hip_bf16.h>

typedef float f32x4 __attribute__((ext_vector_type(4)));
typedef __bf16 bf16x8 __attribute__((ext_vector_type(8)));
typedef unsigned short u16x8 __attribute__((ext_vector_type(8)));

#define GN_EPS 1e-5f
#define LN_EPS 1e-5f
#define COS_EPS_F 1e-8f

__device__ __forceinline__ unsigned short f2bf(float f) {
  unsigned int u = __builtin_bit_cast(unsigned int, f);
  u += 0x7fffu + ((u >> 16) & 1u);   // round-to-nearest-even
  return (unsigned short)(u >> 16);
}

// ---------------------------------------------------------------------------
// Coalesced transpose + bf16 cast: x[b][ci][hw] f32 -> xT[b][hw][ci] bf16.
// Tile: 64 hw x 128 ci. Reads 256B/wave along hw; writes packed uint (2 bf16)
// 256B/wave along ci. LDS [hw][ci] stride 129 -> conflict-free on store,
// 2-way (free) on the float2 read.
// ---------------------------------------------------------------------------
__global__ void transpose_kernel(const float* __restrict__ x,
                                 unsigned short* __restrict__ xT,
                                 unsigned short* __restrict__ zerobuf) {
  __shared__ float lds[64][129];
  int bid = blockIdx.x;                 // b*8 + cit*4 + hwt
  int hwt = bid & 3, cit = (bid >> 2) & 1, b = bid >> 3;
  int hw0 = hwt * 64, ci0 = cit * 128;
  int tid = threadIdx.x;

  if (bid == 0 && tid < 8) zerobuf[tid] = 0;   // 16B zero page for conv border

  int hwx = tid & 63, cy0 = tid >> 6;   // wave id = cy0
  const float* xb = x + (b * 256 + ci0) * 256 + hw0;
  #pragma unroll 8
  for (int p = 0; p < 32; ++p) {
    int cy = cy0 + 4 * p;
    lds[hwx][cy] = xb[cy * 256 + hwx];
  }
  __syncthreads();

  int cp = tid & 63, hy0 = tid >> 6;
  unsigned int* outp = (unsigned int*)(xT + (b * 256 + hw0) * 256 + ci0);
  #pragma unroll 4
  for (int p = 0; p < 16; ++p) {
    int hy = hy0 + 4 * p;
    float lo = lds[hy][2 * cp];
    float hi = lds[hy][2 * cp + 1];
    unsigned int w = ((unsigned int)f2bf(hi) << 16) | f2bf(lo);
    outp[hy * 128 + cp] = w;
  }
}

// ---------------------------------------------------------------------------
// Repack conv weight: W[co][ci][3][3] f32 -> wp[co][9][ci] bf16 (B^T layout)
// ---------------------------------------------------------------------------
__global__ void pack_kernel(const float* __restrict__ w, unsigned short* __restrict__ wp) {
  int idx = blockIdx.x * 256 + threadIdx.x;   // 0..589823
  int ci = idx & 255;
  int rest = idx >> 8;
  int khw = rest % 9, co = rest / 9;
  wp[idx] = f2bf(w[(co * 256 + ci) * 9 + khw]);
}

// ---------------------------------------------------------------------------
// Fused Conv3x3 (implicit GEMM, bf16 MFMA) + bias + GroupNorm(16) + ReLU +
// spatial mean. Block = (b, nt): 256 spatial rows x 128 channels, 8 waves.
// Border pixels redirect the global_load_lds SOURCE to a 16B zero page.
// ---------------------------------------------------------------------------
__device__ __forceinline__ void gl_lds16(const unsigned short* g, unsigned short* l) {
  __builtin_amdgcn_global_load_lds(
      (const __attribute__((address_space(1))) void*)g,
      (__attribute__((address_space(3))) void*)l, 16, 0, 0);
}

__launch_bounds__(512, 2)
__global__ void conv_gn_pool(const unsigned short* __restrict__ xT,
                             const unsigned short* __restrict__ wp,
                             const unsigned short* __restrict__ zb,
                             const float* __restrict__ cbias,
                             const float* __restrict__ gng,
                             const float* __restrict__ gnb,
                             float* __restrict__ enc) {
  __shared__ unsigned short At[256 * 64];   // 32 KB  [row][k] (k-chunks XOR-swizzled by row&7)
  __shared__ unsigned short Bt[128 * 64];   // 16 KB  [co][k]
  __shared__ float gsum[8], gsq[8], pooled[128];

  int bid = blockIdx.x;                     // 0..511
  int swz = (bid & 7) * 64 + (bid >> 3);    // XCD swizzle: both halves of image b on same XCD
  int b = swz >> 1, nt = swz & 1;
  int tid = threadIdx.x;
  int wid = tid >> 6, lane = tid & 63;
  int wr = wid >> 1, wc = wid & 1;          // wave grid 4(M) x 2(N), wave tile 64x64
  int l15 = lane & 15, l4 = lane >> 4;

  if (tid < 8) { gsum[tid] = 0.f; gsq[tid] = 0.f; }
  if (tid < 128) pooled[tid] = 0.f;

  f32x4 acc[4][4];
  #pragma unroll
  for (int i = 0; i < 4; ++i)
    #pragma unroll
    for (int j = 0; j < 4; ++j) acc[i][j] = (f32x4)(0.0f);

  const unsigned short* xb = xT + b * 65536;

  for (int kh = 0; kh < 3; ++kh) {
    for (int kw = 0; kw < 3; ++kw) {
      int khw = kh * 3 + kw;
      for (int ci0 = 0; ci0 < 256; ci0 += 64) {
        // ---- stage A: 256 rows x 64 k (2048 16B-chunks, 4/thread) ----
        #pragma unroll
        for (int it = 0; it < 4; ++it) {
          int s = it * 512 + tid;
          int r = s >> 3, c = s & 7;
          int cs = c ^ (r & 7);            // pre-swizzle the SOURCE chunk (rule 21)
          int h = (r >> 4) + kh - 1;
          int w = (r & 15) + kw - 1;
          const unsigned short* src =
              ((unsigned)h < 16u && (unsigned)w < 16u)
                  ? xb + ((h * 16 + w) * 256 + ci0 + cs * 8)
                  : zb;
          gl_lds16(src, &At[s * 8]);
        }
        // ---- stage B: 128 co x 64 k (1024 chunks, 2/thread) ----
        #pragma unroll
        for (int it = 0; it < 2; ++it) {
          int s = it * 512 + tid;
          int co = s >> 3, c = s & 7;
          int cs = c ^ (co & 7);
          const unsigned short* src =
              wp + ((nt * 128 + co) * 9 + khw) * 256 + ci0 + cs * 8;
          gl_lds16(src, &Bt[s * 8]);
        }
        __syncthreads();                   // compiler drains vmcnt here
        #pragma unroll
        for (int ksub = 0; ksub < 2; ++ksub) {
          int kk = ksub * 32 + l4 * 8;
          bf16x8 af[4], bf[4];
          #pragma unroll
          for (int mf = 0; mf < 4; ++mf) {
            int row = wr * 64 + mf * 16 + l15;
            af[mf] = __builtin_bit_cast(
                bf16x8, *(const u16x8*)&At[row * 64 + (kk ^ ((row & 7) << 3))]);
          }
          #pragma unroll
          for (int nf = 0; nf < 4; ++nf) {
            int co = wc * 64 + nf * 16 + l15;
            bf[nf] = __builtin_bit_cast(
                bf16x8, *(const u16x8*)&Bt[co * 64 + (kk ^ ((co & 7) << 3))]);
          }
          #pragma unroll
          for (int mf = 0; mf < 4; ++mf)
            #pragma unroll
            for (int nf = 0; nf < 4; ++nf)
              acc[mf][nf] = __builtin_amdgcn_mfma_f32_16x16x32_bf16(
                  af[mf], bf[nf], acc[mf][nf], 0, 0, 0);
        }
        __syncthreads();
      }
    }
  }

  // ---- epilogue: +bias, group stats (8 groups fully inside this block) ----
  float bias[4], gg[4], gb[4];
  #pragma unroll
  for (int nf = 0; nf < 4; ++nf) {
    int co = nt * 128 + wc * 64 + nf * 16 + l15;
    bias[nf] = cbias[co]; gg[nf] = gng[co]; gb[nf] = gnb[co];
  }
  #pragma unroll
  for (int nf = 0; nf < 4; ++nf) {
    float s1 = 0.f, s2 = 0.f;
    #pragma unroll
    for (int mf = 0; mf < 4; ++mf)
      #pragma unroll
      for (int i = 0; i < 4; ++i) {
        float v = acc[mf][nf][i] + bias[nf];
        acc[mf][nf][i] = v;
        s1 += v; s2 += v * v;
      }
    #pragma unroll
    for (int d = 1; d < 64; d <<= 1) {
      s1 += __shfl_xor(s1, d);
      s2 += __shfl_xor(s2, d);
    }
    if (lane == 0) {
      atomicAdd(&gsum[wc * 4 + nf], s1);
      atomicAdd(&gsq[wc * 4 + nf], s2);
    }
  }
  __syncthreads();
  // ---- normalize + relu + pool ----
  #pragma unroll
  for (int nf = 0; nf < 4; ++nf) {
    int g = wc * 4 + nf;
    float mean = gsum[g] * (1.f / 4096.f);
    float var = gsq[g] * (1.f / 4096.f) - mean * mean;
    float rs = rsqrtf(var + GN_EPS);
    float p = 0.f;
    #pragma unroll
    for (int mf = 0; mf < 4; ++mf)
      #pragma unroll
      for (int i = 0; i < 4; ++i) {
        float v = (acc[mf][nf][i] - mean) * rs * gg[nf] + gb[nf];
        p += fmaxf(v, 0.f);
      }
    p += __shfl_xor(p, 16);
    p += __shfl_xor(p, 32);
    if (lane < 16) atomicAdd(&pooled[wc * 64 + nf * 16 + l15], p);
  }
  __syncthreads();
  if (tid < 128)
    enc[b * 256 + nt * 128 + tid] = pooled[tid] * (1.f / 256.f);
}

// ---------------------------------------------------------------------------
// Projector + LN + l2norm + predictor. One block per row (768 rows).
// ---------------------------------------------------------------------------
__global__ void proj_pred(const float* __restrict__ enc,
                          const float* __restrict__ w1, const float* __restrict__ b1,
                          const float* __restrict__ w2, const float* __restrict__ b2,
                          const float* __restrict__ lng, const float* __restrict__ lnb,
                          const float* __restrict__ pw1, const float* __restrict__ pb1,
                          const float* __restrict__ pw2, const float* __restrict__ pb2,
                          float* __restrict__ proj, float* __restrict__ pred,
                          float* __restrict__ znorm) {
  __shared__ float row[256], h1[256], zz[128], p1[128], red[2];
  int r = blockIdx.x, tid = threadIdx.x;
  row[tid] = enc[r * 256 + tid];
  __syncthreads();
  float a = 0.f;
  for (int k = 0; k < 256; ++k) a += row[k] * w1[k * 256 + tid];
  h1[tid] = fmaxf(a + b1[tid], 0.f);
  __syncthreads();
  if (tid < 128) {
    a = 0.f;
    for (int k = 0; k < 256; ++k) a += h1[k] * w2[k * 128 + tid];
    zz[tid] = a + b2[tid];
  }
  __syncthreads();
  if (tid == 0) {
    float m = 0.f;
    for (int k = 0; k < 128; ++k) m += zz[k];
    m *= (1.f / 128.f);
    float v = 0.f;
    for (int k = 0; k < 128; ++k) { float d = zz[k] - m; v += d * d; }
    red[0] = m;
    red[1] = rsqrtf(v * (1.f / 128.f) + LN_EPS);
  }
  __syncthreads();
  float zval = 0.f;
  if (tid < 128) {
    zval = (zz[tid] - red[0]) * red[1] * lng[tid] + lnb[tid];
    proj[r * 128 + tid] = zval;
  }
  __syncthreads();
  if (tid < 128) zz[tid] = zval;     // zz now holds LN output
  __syncthreads();
  if (tid == 0) {
    float s = 0.f;
    for (int k = 0; k < 128; ++k) s += zz[k] * zz[k];
    red[0] = 1.f / fmaxf(sqrtf(s), COS_EPS_F);
  }
  __syncthreads();
  if (tid < 128) {
    znorm[r * 128 + tid] = zz[tid] * red[0];
    a = 0.f;
    for (int k = 0; k < 128; ++k) a += zz[k] * pw1[k * 128 + tid];
    p1[tid] = fmaxf(a + pb1[tid], 0.f);
  }
  __syncthreads();
  if (tid < 128) {
    a = 0.f;
    for (int k = 0; k < 128; ++k) a += p1[k] * pw2[k * 128 + tid];
    pred[r * 128 + tid] = a + pb2[tid];
  }
}

// ---------------------------------------------------------------------------
// Loss: block = (pair, k). lse(S[k,:]) - S[k,k] per row; partials to ws.
// ---------------------------------------------------------------------------
__global__ void loss_kernel(const float* __restrict__ zn, float* __restrict__ part) {
  __shared__ float zi[128], sv[256], rbuf[256];
  int blk = blockIdx.x;           // p*256 + k
  int p = blk >> 8, k = blk & 255;
  int i = (p == 2) ? 1 : 0;
  int j = (p == 0) ? 1 : 2;
  int tid = threadIdx.x;
  if (tid < 128) zi[tid] = zn[(i * 256 + k) * 128 + tid];
  __syncthreads();
  const float4* zj = (const float4*)&zn[(j * 256 + tid) * 128];
  float s = 0.f;
  #pragma unroll 8
  for (int d = 0; d < 32; ++d) {
    float4 aq = *(const float4*)&zi[d * 4];
    float4 bq = zj[d];
    s += aq.x * bq.x + aq.y * bq.y + aq.z * bq.z + aq.w * bq.w;
  }
  s *= 10.0f;                      // 1/TEMP
  sv[tid] = s;
  rbuf[tid] = s;
  __syncthreads();
  for (int d = 128; d > 0; d >>= 1) {
    if (tid < d) rbuf[tid] = fmaxf(rbuf[tid], rbuf[tid + d]);
    __syncthreads();
  }
  float m = rbuf[0];
  __syncthreads();
  rbuf[tid] = expf(s - m);
  __syncthreads();
  for (int d = 128; d > 0; d >>= 1) {
    if (tid < d) rbuf[tid] += rbuf[tid + d];
    __syncthreads();
  }
  if (tid == 0) part[blk] = m + logf(rbuf[0]) - sv[k];
}

__global__ void finalize_loss(const float* __restrict__ part, float* __restrict__ out) {
  __shared__ float red[256];
  int tid = threadIdx.x;
  float s = 0.f;
  for (int idx = tid; idx < 768; idx += 256) s += part[idx];
  red[tid] = s;
  __syncthreads();
  for (int d = 128; d > 0; d >>= 1) {
    if (tid < d) red[tid] += red[tid + d];
    __syncthreads();
  }
  if (tid == 0) out[0] = red[0] * (1.f / 768.f);
}

// ---------------------------------------------------------------------------
extern "C" void kernel_launch(void* const* d_in, const int* in_sizes, int n_in,
                              void* d_out, int out_size, void* d_ws, size_t ws_size,
                              hipStream_t stream) {
  const float* x[3]  = {(const float*)d_in[0], (const float*)d_in[1], (const float*)d_in[2]};
  const float* cw[3] = {(const float*)d_in[3], (const float*)d_in[7], (const float*)d_in[11]};
  const float* cb[3] = {(const float*)d_in[4], (const float*)d_in[8], (const float*)d_in[12]};
  const float* gg[3] = {(const float*)d_in[5], (const float*)d_in[9], (const float*)d_in[13]};
  const float* gb[3] = {(const float*)d_in[6], (const float*)d_in[10], (const float*)d_in[14]};
  const float* p_w1 = (const float*)d_in[15];
  const float* p_b1 = (const float*)d_in[16];
  const float* p_w2 = (const float*)d_in[17];
  const float* p_b2 = (const float*)d_in[18];
  const float* ln_g = (const float*)d_in[19];
  const float* ln_b = (const float*)d_in[20];
  const float* q_w1 = (const float*)d_in[21];
  const float* q_b1 = (const float*)d_in[22];
  const float* q_w2 = (const float*)d_in[23];
  const float* q_b2 = (const float*)d_in[24];

  float* out = (float*)d_out;
  char* ws = (char*)d_ws;
  unsigned short* xT  = (unsigned short*)ws;                  // 33,554,432 B
  unsigned short* wpk = (unsigned short*)(ws + 33554432);     //  1,179,648 B
  float* znorm = (float*)(ws + 34734080);                     //    393,216 B
  float* part  = (float*)(ws + 35127296);                     //      3,072 B
  unsigned short* zb = (unsigned short*)(ws + 35130368);      //         64 B

  float* enc  = out;              // [3][256][256]
  float* proj = out + 196608;     // [3][256][128]
  float* pred = out + 294912;     // [3][256][128]
  float* lossp = out + 393216;    // scalar

  for (int m = 0; m < 3; ++m) {
    transpose_kernel<<<dim3(2048), dim3(256), 0, stream>>>(x[m], xT, zb);
    pack_kernel<<<dim3(2304), dim3(256), 0, stream>>>(cw[m], wpk);
    conv_gn_pool<<<dim3(512), dim3(512), 0, stream>>>(xT, wpk, zb, cb[m], gg[m], gb[m],
                                                      enc + m * 65536);
  }
  proj_pred<<<dim3(768), dim3(256), 0, stream>>>(enc, p_w1, p_b1, p_w2, p_b2, ln_g, ln_b,
                                                 q_w1, q_b1, q_w2, q_b2, proj, pred, znorm);
  loss_kernel<<<dim3(768), dim3(256), 0, stream>>>(znorm, part);
  finalize_loss<<<dim3(1), dim3(256), 0, stream>>>(part, lossp);
}

// Round 3
// 335.627 us; speedup vs baseline: 2.1917x; 1.1617x over previous
//
#include <hip/hip_runtime.h>
#include <hip/hip_bf16.h>

typedef float f32x4 __attribute__((ext_vector_type(4)));
typedef __bf16 bf16x8 __attribute__((ext_vector_type(8)));
typedef unsigned short u16x8 __attribute__((ext_vector_type(8)));

#define GN_EPS 1e-5f
#define LN_EPS 1e-5f
#define COS_EPS_F 1e-8f

__device__ __forceinline__ unsigned short f2bf(float f) {
  unsigned int u = __builtin_bit_cast(unsigned int, f);
  u += 0x7fffu + ((u >> 16) & 1u);   // round-to-nearest-even
  return (unsigned short)(u >> 16);
}

// ---------------------------------------------------------------------------
// Coalesced transpose + bf16 cast: x[b][ci][hw] f32 -> xT[b][hw][ci] bf16.
// ---------------------------------------------------------------------------
__global__ void transpose_kernel(const float* __restrict__ x,
                                 unsigned short* __restrict__ xT) {
  __shared__ float lds[64][129];
  int bid = blockIdx.x;                 // b*8 + cit*4 + hwt
  int hwt = bid & 3, cit = (bid >> 2) & 1, b = bid >> 3;
  int hw0 = hwt * 64, ci0 = cit * 128;
  int tid = threadIdx.x;

  int hwx = tid & 63, cy0 = tid >> 6;
  const float* xb = x + (b * 256 + ci0) * 256 + hw0;
  #pragma unroll 8
  for (int p = 0; p < 32; ++p) {
    int cy = cy0 + 4 * p;
    lds[hwx][cy] = xb[cy * 256 + hwx];
  }
  __syncthreads();

  int cp = tid & 63, hy0 = tid >> 6;
  unsigned int* outp = (unsigned int*)(xT + (b * 256 + hw0) * 256 + ci0);
  #pragma unroll 4
  for (int p = 0; p < 16; ++p) {
    int hy = hy0 + 4 * p;
    float lo = lds[hy][2 * cp];
    float hi = lds[hy][2 * cp + 1];
    unsigned int w = ((unsigned int)f2bf(hi) << 16) | f2bf(lo);
    outp[hy * 128 + cp] = w;
  }
}

// ---------------------------------------------------------------------------
// Repack conv weight: W[co][ci][3][3] f32 -> wp[co][9][ci] bf16 (B^T layout)
// ---------------------------------------------------------------------------
__global__ void pack_kernel(const float* __restrict__ w, unsigned short* __restrict__ wp,
                            unsigned short* __restrict__ zerobuf) {
  int idx = blockIdx.x * 256 + threadIdx.x;   // 0..589823
  if (blockIdx.x == 0 && threadIdx.x < 8) zerobuf[threadIdx.x] = 0;
  int ci = idx & 255;
  int rest = idx >> 8;
  int khw = rest % 9, co = rest / 9;
  wp[idx] = f2bf(w[(co * 256 + ci) * 9 + khw]);
}

// ---------------------------------------------------------------------------
// Fused Conv3x3 (implicit GEMM, bf16 MFMA) + bias + GroupNorm(16) + ReLU +
// spatial mean.  One block = one image: 256 spatial x 256 co, K=2304.
// Pipelined: BK=32, 4 LDS buffers, stage tile t+2 during tile t,
// counted s_waitcnt vmcnt(4) once per tile (never 0 in steady state).
// ---------------------------------------------------------------------------
__device__ __forceinline__ void gl_lds16(const unsigned short* g, unsigned short* l) {
  __builtin_amdgcn_global_load_lds(
      (const __attribute__((address_space(1))) void*)g,
      (__attribute__((address_space(3))) void*)l, 16, 0, 0);
}

__launch_bounds__(512, 2)
__global__ void conv_gn_pool(const unsigned short* __restrict__ xT,
                             const unsigned short* __restrict__ wp,
                             const unsigned short* __restrict__ zb,
                             const float* __restrict__ cbias,
                             const float* __restrict__ gng,
                             const float* __restrict__ gnb,
                             float* __restrict__ enc) {
  __shared__ unsigned short Ab[4][8192];   // 64 KB: 4 bufs x (256 rows x 32 k)
  __shared__ unsigned short Bb[4][8192];   // 64 KB: 4 bufs x (256 co  x 32 k)
  __shared__ float gsum[16], gsq[16], pooled[256];

  int bid = blockIdx.x;                    // 0..255, one image each
  int b = (bid & 7) * 32 + (bid >> 3);     // XCD swizzle (bijective, 256%8==0)
  int tid = threadIdx.x;
  int wid = tid >> 6, lane = tid & 63;
  int wr = wid >> 2, wc = wid & 3;         // wave grid 2(M) x 4(N); wave tile 128x64
  int l15 = lane & 15, l4 = lane >> 4;

  if (tid < 16) { gsum[tid] = 0.f; gsq[tid] = 0.f; }
  if (tid < 256) pooled[tid] = 0.f;

  // ---- staging geometry: 1024 16B-chunks per tile, 2 per thread ----
  int s0 = tid, s1 = 512 + tid;
  int r0 = s0 >> 2, c0 = s0 & 3;           // row/co 0..255, chunk 0..3
  int r1 = s1 >> 2, c1 = s1 & 3;
  int cs0 = (c0 ^ (r0 & 3)) * 8;           // source pre-swizzle (rule 21)
  int cs1 = (c1 ^ (r1 & 3)) * 8;
  int rh0 = r0 >> 4, rw0 = r0 & 15;
  int rh1 = r1 >> 4, rw1 = r1 & 15;

  const unsigned short* xb = xT + b * 65536;
  const unsigned short* bB0 = wp + r0 * 2304 + cs0;   // co*9*256 + swz-chunk
  const unsigned short* bB1 = wp + r1 * 2304 + cs1;

  // ---- LDS read offsets (ushort units); row&3 == l15&3 for all frags ----
  int kch = (l4 ^ (l15 & 3)) * 8;
  int base_af = (wr * 128 + l15) * 32 + kch;
  int base_bf = (wc * 64 + l15) * 32 + kch;

  f32x4 acc[8][4];
  #pragma unroll
  for (int i = 0; i < 8; ++i)
    #pragma unroll
    for (int j = 0; j < 4; ++j) acc[i][j] = (f32x4)(0.0f);

  // ---- stage helpers ----
  #define STAGE_A(T2)                                                          \
    {                                                                          \
      int khw_ = (T2) >> 3, kc_ = (T2) & 7;                                    \
      int kh_ = khw_ / 3, kw_ = khw_ - kh_ * 3;                                \
      int ci0_ = kc_ * 32;                                                     \
      unsigned short* dst_ = &Ab[(T2) & 3][0];                                 \
      int h0_ = rh0 + kh_ - 1, w0_ = rw0 + kw_ - 1;                            \
      const unsigned short* sA0 = ((unsigned)h0_ < 16u && (unsigned)w0_ < 16u) \
          ? xb + ((h0_ * 16 + w0_) * 256 + ci0_ + cs0) : zb;                   \
      gl_lds16(sA0, dst_ + s0 * 8);                                            \
      int h1_ = rh1 + kh_ - 1, w1_ = rw1 + kw_ - 1;                            \
      const unsigned short* sA1 = ((unsigned)h1_ < 16u && (unsigned)w1_ < 16u) \
          ? xb + ((h1_ * 16 + w1_) * 256 + ci0_ + cs1) : zb;                   \
      gl_lds16(sA1, dst_ + s1 * 8);                                            \
    }
  #define STAGE_B(T2)                                                          \
    {                                                                          \
      int off_ = ((T2) >> 3) * 256 + ((T2) & 7) * 32;                          \
      unsigned short* dst_ = &Bb[(T2) & 3][0];                                 \
      gl_lds16(bB0 + off_, dst_ + s0 * 8);                                     \
      gl_lds16(bB1 + off_, dst_ + s1 * 8);                                     \
    }

  // ---- prologue: tiles 0 and 1 in flight ----
  STAGE_A(0); STAGE_B(0); STAGE_A(1); STAGE_B(1);
  asm volatile("s_waitcnt vmcnt(4)" ::: "memory");   // tile 0 landed; tile 1 in flight
  __builtin_amdgcn_s_barrier();

  for (int t = 0; t < 72; ++t) {
    const unsigned short* Ap = &Ab[t & 3][0];
    const unsigned short* Bp = &Bb[t & 3][0];
    int tp2 = t + 2;
    // ================= phase 0: mf 0..3 =================
    bf16x8 af0[4], bfr[4];
    #pragma unroll
    for (int j = 0; j < 4; ++j)
      af0[j] = __builtin_bit_cast(bf16x8, *(const u16x8*)&Ap[base_af + j * 512]);
    #pragma unroll
    for (int n = 0; n < 4; ++n)
      bfr[n] = __builtin_bit_cast(bf16x8, *(const u16x8*)&Bp[base_bf + n * 512]);
    if (tp2 < 72) STAGE_A(tp2);
    __builtin_amdgcn_s_barrier();
    __builtin_amdgcn_s_setprio(1);
    #pragma unroll
    for (int j = 0; j < 4; ++j)
      #pragma unroll
      for (int n = 0; n < 4; ++n)
        acc[j][n] = __builtin_amdgcn_mfma_f32_16x16x32_bf16(af0[j], bfr[n], acc[j][n], 0, 0, 0);
    __builtin_amdgcn_s_setprio(0);
    __builtin_amdgcn_s_barrier();
    // ================= phase 1: mf 4..7 =================
    bf16x8 af1[4];
    #pragma unroll
    for (int j = 0; j < 4; ++j)
      af1[j] = __builtin_bit_cast(bf16x8, *(const u16x8*)&Ap[base_af + (4 + j) * 512]);
    if (tp2 < 72) STAGE_B(tp2);
    if (t < 69) asm volatile("s_waitcnt vmcnt(4)" ::: "memory");   // t+1 landed, t+2 in flight
    else        asm volatile("s_waitcnt vmcnt(0)" ::: "memory");   // drain tail
    __builtin_amdgcn_s_barrier();
    __builtin_amdgcn_s_setprio(1);
    #pragma unroll
    for (int j = 0; j < 4; ++j)
      #pragma unroll
      for (int n = 0; n < 4; ++n)
        acc[4 + j][n] = __builtin_amdgcn_mfma_f32_16x16x32_bf16(af1[j], bfr[n], acc[4 + j][n], 0, 0, 0);
    __builtin_amdgcn_s_setprio(0);
    __builtin_amdgcn_s_barrier();
  }
  #undef STAGE_A
  #undef STAGE_B

  // ---- epilogue: +bias, group stats (16 groups fully inside this block) ----
  float bias[4], ggv[4], gbv[4];
  #pragma unroll
  for (int nf = 0; nf < 4; ++nf) {
    int co = wc * 64 + nf * 16 + l15;
    bias[nf] = cbias[co]; ggv[nf] = gng[co]; gbv[nf] = gnb[co];
  }
  #pragma unroll
  for (int nf = 0; nf < 4; ++nf) {
    float s1 = 0.f, s2 = 0.f;
    #pragma unroll
    for (int mf = 0; mf < 8; ++mf)
      #pragma unroll
      for (int i = 0; i < 4; ++i) {
        float v = acc[mf][nf][i] + bias[nf];
        acc[mf][nf][i] = v;
        s1 += v; s2 += v * v;
      }
    #pragma unroll
    for (int d = 1; d < 64; d <<= 1) {
      s1 += __shfl_xor(s1, d);
      s2 += __shfl_xor(s2, d);
    }
    if (lane == 0) {
      atomicAdd(&gsum[wc * 4 + nf], s1);
      atomicAdd(&gsq[wc * 4 + nf], s2);
    }
  }
  __syncthreads();
  // ---- normalize + relu + pool ----
  #pragma unroll
  for (int nf = 0; nf < 4; ++nf) {
    int g = wc * 4 + nf;
    float mean = gsum[g] * (1.f / 4096.f);
    float var = gsq[g] * (1.f / 4096.f) - mean * mean;
    float rs = rsqrtf(var + GN_EPS);
    float p = 0.f;
    #pragma unroll
    for (int mf = 0; mf < 8; ++mf)
      #pragma unroll
      for (int i = 0; i < 4; ++i) {
        float v = (acc[mf][nf][i] - mean) * rs * ggv[nf] + gbv[nf];
        p += fmaxf(v, 0.f);
      }
    p += __shfl_xor(p, 16);
    p += __shfl_xor(p, 32);
    if (lane < 16) atomicAdd(&pooled[wc * 64 + nf * 16 + l15], p);
  }
  __syncthreads();
  if (tid < 256)
    enc[b * 256 + tid] = pooled[tid] * (1.f / 256.f);
}

// ---------------------------------------------------------------------------
// Projector + LN + l2norm + predictor. One block per row (768 rows).
// ---------------------------------------------------------------------------
__global__ void proj_pred(const float* __restrict__ enc,
                          const float* __restrict__ w1, const float* __restrict__ b1,
                          const float* __restrict__ w2, const float* __restrict__ b2,
                          const float* __restrict__ lng, const float* __restrict__ lnb,
                          const float* __restrict__ pw1, const float* __restrict__ pb1,
                          const float* __restrict__ pw2, const float* __restrict__ pb2,
                          float* __restrict__ proj, float* __restrict__ pred,
                          float* __restrict__ znorm) {
  __shared__ float row[256], h1[256], zz[128], p1[128], red[2];
  int r = blockIdx.x, tid = threadIdx.x;
  row[tid] = enc[r * 256 + tid];
  __syncthreads();
  float a = 0.f;
  for (int k = 0; k < 256; ++k) a += row[k] * w1[k * 256 + tid];
  h1[tid] = fmaxf(a + b1[tid], 0.f);
  __syncthreads();
  if (tid < 128) {
    a = 0.f;
    for (int k = 0; k < 256; ++k) a += h1[k] * w2[k * 128 + tid];
    zz[tid] = a + b2[tid];
  }
  __syncthreads();
  if (tid == 0) {
    float m = 0.f;
    for (int k = 0; k < 128; ++k) m += zz[k];
    m *= (1.f / 128.f);
    float v = 0.f;
    for (int k = 0; k < 128; ++k) { float d = zz[k] - m; v += d * d; }
    red[0] = m;
    red[1] = rsqrtf(v * (1.f / 128.f) + LN_EPS);
  }
  __syncthreads();
  float zval = 0.f;
  if (tid < 128) {
    zval = (zz[tid] - red[0]) * red[1] * lng[tid] + lnb[tid];
    proj[r * 128 + tid] = zval;
  }
  __syncthreads();
  if (tid < 128) zz[tid] = zval;     // zz now holds LN output
  __syncthreads();
  if (tid == 0) {
    float s = 0.f;
    for (int k = 0; k < 128; ++k) s += zz[k] * zz[k];
    red[0] = 1.f / fmaxf(sqrtf(s), COS_EPS_F);
  }
  __syncthreads();
  if (tid < 128) {
    znorm[r * 128 + tid] = zz[tid] * red[0];
    a = 0.f;
    for (int k = 0; k < 128; ++k) a += zz[k] * pw1[k * 128 + tid];
    p1[tid] = fmaxf(a + pb1[tid], 0.f);
  }
  __syncthreads();
  if (tid < 128) {
    a = 0.f;
    for (int k = 0; k < 128; ++k) a += p1[k] * pw2[k * 128 + tid];
    pred[r * 128 + tid] = a + pb2[tid];
  }
}

// ---------------------------------------------------------------------------
// Loss: block = (pair, k). lse(S[k,:]) - S[k,k] per row; partials to ws.
// ---------------------------------------------------------------------------
__global__ void loss_kernel(const float* __restrict__ zn, float* __restrict__ part) {
  __shared__ float zi[128], sv[256], rbuf[256];
  int blk = blockIdx.x;           // p*256 + k
  int p = blk >> 8, k = blk & 255;
  int i = (p == 2) ? 1 : 0;
  int j = (p == 0) ? 1 : 2;
  int tid = threadIdx.x;
  if (tid < 128) zi[tid] = zn[(i * 256 + k) * 128 + tid];
  __syncthreads();
  const float4* zj = (const float4*)&zn[(j * 256 + tid) * 128];
  float s = 0.f;
  #pragma unroll 8
  for (int d = 0; d < 32; ++d) {
    float4 aq = *(const float4*)&zi[d * 4];
    float4 bq = zj[d];
    s += aq.x * bq.x + aq.y * bq.y + aq.z * bq.z + aq.w * bq.w;
  }
  s *= 10.0f;                      // 1/TEMP
  sv[tid] = s;
  rbuf[tid] = s;
  __syncthreads();
  for (int d = 128; d > 0; d >>= 1) {
    if (tid < d) rbuf[tid] = fmaxf(rbuf[tid], rbuf[tid + d]);
    __syncthreads();
  }
  float m = rbuf[0];
  __syncthreads();
  rbuf[tid] = expf(s - m);
  __syncthreads();
  for (int d = 128; d > 0; d >>= 1) {
    if (tid < d) rbuf[tid] += rbuf[tid + d];
    __syncthreads();
  }
  if (tid == 0) part[blk] = m + logf(rbuf[0]) - sv[k];
}

__global__ void finalize_loss(const float* __restrict__ part, float* __restrict__ out) {
  __shared__ float red[256];
  int tid = threadIdx.x;
  float s = 0.f;
  for (int idx = tid; idx < 768; idx += 256) s += part[idx];
  red[tid] = s;
  __syncthreads();
  for (int d = 128; d > 0; d >>= 1) {
    if (tid < d) red[tid] += red[tid + d];
    __syncthreads();
  }
  if (tid == 0) out[0] = red[0] * (1.f / 768.f);
}

// ---------------------------------------------------------------------------
extern "C" void kernel_launch(void* const* d_in, const int* in_sizes, int n_in,
                              void* d_out, int out_size, void* d_ws, size_t ws_size,
                              hipStream_t stream) {
  const float* x[3]  = {(const float*)d_in[0], (const float*)d_in[1], (const float*)d_in[2]};
  const float* cw[3] = {(const float*)d_in[3], (const float*)d_in[7], (const float*)d_in[11]};
  const float* cb[3] = {(const float*)d_in[4], (const float*)d_in[8], (const float*)d_in[12]};
  const float* gg[3] = {(const float*)d_in[5], (const float*)d_in[9], (const float*)d_in[13]};
  const float* gb[3] = {(const float*)d_in[6], (const float*)d_in[10], (const float*)d_in[14]};
  const float* p_w1 = (const float*)d_in[15];
  const float* p_b1 = (const float*)d_in[16];
  const float* p_w2 = (const float*)d_in[17];
  const float* p_b2 = (const float*)d_in[18];
  const float* ln_g = (const float*)d_in[19];
  const float* ln_b = (const float*)d_in[20];
  const float* q_w1 = (const float*)d_in[21];
  const float* q_b1 = (const float*)d_in[22];
  const float* q_w2 = (const float*)d_in[23];
  const float* q_b2 = (const float*)d_in[24];

  float* out = (float*)d_out;
  char* ws = (char*)d_ws;
  unsigned short* xT  = (unsigned short*)ws;                  // 33,554,432 B
  unsigned short* wpk = (unsigned short*)(ws + 33554432);     //  1,179,648 B
  float* znorm = (float*)(ws + 34734080);                     //    393,216 B
  float* part  = (float*)(ws + 35127296);                     //      3,072 B
  unsigned short* zb = (unsigned short*)(ws + 35130368);      //         64 B

  float* enc  = out;              // [3][256][256]
  float* proj = out + 196608;     // [3][256][128]
  float* pred = out + 294912;     // [3][256][128]
  float* lossp = out + 393216;    // scalar

  for (int m = 0; m < 3; ++m) {
    transpose_kernel<<<dim3(2048), dim3(256), 0, stream>>>(x[m], xT);
    pack_kernel<<<dim3(2304), dim3(256), 0, stream>>>(cw[m], wpk, zb);
    conv_gn_pool<<<dim3(256), dim3(512), 0, stream>>>(xT, wpk, zb, cb[m], gg[m], gb[m],
                                                      enc + m * 65536);
  }
  proj_pred<<<dim3(768), dim3(256), 0, stream>>>(enc, p_w1, p_b1, p_w2, p_b2, ln_g, ln_b,
                                                 q_w1, q_b1, q_w2, q_b2, proj, pred, znorm);
  loss_kernel<<<dim3(768), dim3(256), 0, stream>>>(znorm, part);
  finalize_loss<<<dim3(1), dim3(256), 0, stream>>>(part, lossp);
}

// Round 4
// 318.435 us; speedup vs baseline: 2.3100x; 1.0540x over previous
//
#include <hip/hip_runtime.h>
#include <hip/hip_bf16.h>

typedef float f32x4 __attribute__((ext_vector_type(4)));
typedef __bf16 bf16x8 __attribute__((ext_vector_type(8)));
typedef unsigned short u16x8 __attribute__((ext_vector_type(8)));

#define GN_EPS 1e-5f
#define LN_EPS 1e-5f
#define COS_EPS_F 1e-8f

__device__ __forceinline__ unsigned short f2bf(float f) {
  unsigned int u = __builtin_bit_cast(unsigned int, f);
  u += 0x7fffu + ((u >> 16) & 1u);   // round-to-nearest-even
  return (unsigned short)(u >> 16);
}

// ---------------------------------------------------------------------------
// Coalesced transpose + bf16 cast: x[b][ci][hw] f32 -> xT(+m*stride)[b][hw][ci].
// grid = 2048 per image (mBase fixed) or 6144 (3 images, m = bid>>11).
// ---------------------------------------------------------------------------
__global__ void transpose_kernel(const float* __restrict__ x0,
                                 const float* __restrict__ x1,
                                 const float* __restrict__ x2,
                                 unsigned short* __restrict__ xT,
                                 unsigned int strideElems, int mBase) {
  __shared__ float lds[64][129];
  int m = mBase + (blockIdx.x >> 11);
  int bid = blockIdx.x & 2047;          // b*8 + cit*4 + hwt
  const float* x = (m == 0) ? x0 : ((m == 1) ? x1 : x2);
  unsigned short* dst = xT + (unsigned int)(m - mBase) * strideElems;

  int hwt = bid & 3, cit = (bid >> 2) & 1, b = bid >> 3;
  int hw0 = hwt * 64, ci0 = cit * 128;
  int tid = threadIdx.x;

  int hwx = tid & 63, cy0 = tid >> 6;
  const float* xb = x + (b * 256 + ci0) * 256 + hw0;
  #pragma unroll 8
  for (int p = 0; p < 32; ++p) {
    int cy = cy0 + 4 * p;
    lds[hwx][cy] = xb[cy * 256 + hwx];
  }
  __syncthreads();

  int cp = tid & 63, hy0 = tid >> 6;
  unsigned int* outp = (unsigned int*)(dst + (b * 256 + hw0) * 256 + ci0);
  #pragma unroll 4
  for (int p = 0; p < 16; ++p) {
    int hy = hy0 + 4 * p;
    float lo = lds[hy][2 * cp];
    float hi = lds[hy][2 * cp + 1];
    unsigned int w = ((unsigned int)f2bf(hi) << 16) | f2bf(lo);
    outp[hy * 128 + cp] = w;
  }
}

// ---------------------------------------------------------------------------
// Repack conv weights (all 3): W[co][ci][3][3] f32 -> wp[m][co][9][ci] bf16
// grid = dim3(2304, 3)
// ---------------------------------------------------------------------------
__global__ void pack_kernel(const float* __restrict__ w0,
                            const float* __restrict__ w1,
                            const float* __restrict__ w2,
                            unsigned short* __restrict__ wp,
                            unsigned short* __restrict__ zerobuf) {
  int m = blockIdx.y;
  const float* w = (m == 0) ? w0 : ((m == 1) ? w1 : w2);
  int idx = blockIdx.x * 256 + threadIdx.x;   // 0..589823
  if (m == 0 && blockIdx.x == 0 && threadIdx.x < 8) zerobuf[threadIdx.x] = 0;
  int ci = idx & 255;
  int rest = idx >> 8;
  int khw = rest % 9, co = rest / 9;
  wp[m * 589824 + idx] = f2bf(w[(co * 256 + ci) * 9 + khw]);
}

// ---------------------------------------------------------------------------
// Fused Conv3x3 (implicit GEMM, bf16 MFMA) + bias + GroupNorm(16) + ReLU +
// spatial mean.  One block = one image: 256 spatial x 256 co, K=2304.
// Pipelined: BK=32, 4 LDS buffers, stage tile t+2 during tile t,
// counted s_waitcnt vmcnt(4) once per tile (never 0 in steady state).
// Swizzle: chunk c of row r stored at slot c ^ ((r>>1)&3)  (2-way = free).
// grid = 768 (merged, m = bid>>8) or 256 (fallback, m = mBase).
// ---------------------------------------------------------------------------
__device__ __forceinline__ void gl_lds16(const unsigned short* g, unsigned short* l) {
  __builtin_amdgcn_global_load_lds(
      (const __attribute__((address_space(1))) void*)g,
      (__attribute__((address_space(3))) void*)l, 16, 0, 0);
}

__launch_bounds__(512, 2)
__global__ void conv_gn_pool(const unsigned short* __restrict__ xT,
                             unsigned int xTstride,
                             const unsigned short* __restrict__ wp,
                             const unsigned short* __restrict__ zb,
                             const float* __restrict__ cb0, const float* __restrict__ cb1,
                             const float* __restrict__ cb2,
                             const float* __restrict__ gg0, const float* __restrict__ gg1,
                             const float* __restrict__ gg2,
                             const float* __restrict__ gb0, const float* __restrict__ gb1,
                             const float* __restrict__ gb2,
                             float* __restrict__ enc, int mBase) {
  __shared__ unsigned short Ab[4][8192];   // 64 KB: 4 bufs x (256 rows x 32 k)
  __shared__ unsigned short Bb[4][8192];   // 64 KB: 4 bufs x (256 co  x 32 k)
  __shared__ float gsum[16], gsq[16], pooled[256];

  int mm = mBase + (blockIdx.x >> 8);
  int bb = blockIdx.x & 255;
  int b = (bb & 7) * 32 + (bb >> 3);       // XCD swizzle (bijective, 256%8==0)
  const float* cbias = (mm == 0) ? cb0 : ((mm == 1) ? cb1 : cb2);
  const float* gng   = (mm == 0) ? gg0 : ((mm == 1) ? gg1 : gg2);
  const float* gnb   = (mm == 0) ? gb0 : ((mm == 1) ? gb1 : gb2);

  int tid = threadIdx.x;
  int wid = tid >> 6, lane = tid & 63;
  int wr = wid >> 2, wc = wid & 3;         // wave grid 2(M) x 4(N); wave tile 128x64
  int l15 = lane & 15, l4 = lane >> 4;

  if (tid < 16) { gsum[tid] = 0.f; gsq[tid] = 0.f; }
  if (tid < 256) pooled[tid] = 0.f;

  // ---- staging geometry: 1024 16B-chunks per tile, 2 per thread ----
  int s0 = tid, s1 = 512 + tid;
  int r0 = s0 >> 2, c0 = s0 & 3;           // row/co 0..255, chunk 0..3
  int r1 = s1 >> 2, c1 = s1 & 3;
  int cs0 = (c0 ^ ((r0 >> 1) & 3)) * 8;    // source pre-swizzle (rule 21)
  int cs1 = (c1 ^ ((r1 >> 1) & 3)) * 8;
  int rh0 = r0 >> 4, rw0 = r0 & 15;
  int rh1 = r1 >> 4, rw1 = r1 & 15;

  const unsigned short* xb = xT + (unsigned int)(mm - mBase) * xTstride + b * 65536;
  const unsigned short* wpm = wp + mm * 589824;
  const unsigned short* bB0 = wpm + r0 * 2304 + cs0;   // co*9*256 + swz-chunk
  const unsigned short* bB1 = wpm + r1 * 2304 + cs1;

  // ---- LDS read offsets (ushort units); (row>>1)&3 == (l15>>1)&3 ----
  int kch = (l4 ^ ((l15 >> 1) & 3)) * 8;
  int base_af = (wr * 128 + l15) * 32 + kch;
  int base_bf = (wc * 64 + l15) * 32 + kch;

  f32x4 acc[8][4];
  #pragma unroll
  for (int i = 0; i < 8; ++i)
    #pragma unroll
    for (int j = 0; j < 4; ++j) acc[i][j] = (f32x4)(0.0f);

  // ---- stage helpers ----
  #define STAGE_A(T2)                                                          \
    {                                                                          \
      int khw_ = (T2) >> 3, kc_ = (T2) & 7;                                    \
      int kh_ = khw_ / 3, kw_ = khw_ - kh_ * 3;                                \
      int ci0_ = kc_ * 32;                                                     \
      unsigned short* dst_ = &Ab[(T2) & 3][0];                                 \
      int h0_ = rh0 + kh_ - 1, w0_ = rw0 + kw_ - 1;                            \
      const unsigned short* sA0 = ((unsigned)h0_ < 16u && (unsigned)w0_ < 16u) \
          ? xb + ((h0_ * 16 + w0_) * 256 + ci0_ + cs0) : zb;                   \
      gl_lds16(sA0, dst_ + s0 * 8);                                            \
      int h1_ = rh1 + kh_ - 1, w1_ = rw1 + kw_ - 1;                            \
      const unsigned short* sA1 = ((unsigned)h1_ < 16u && (unsigned)w1_ < 16u) \
          ? xb + ((h1_ * 16 + w1_) * 256 + ci0_ + cs1) : zb;                   \
      gl_lds16(sA1, dst_ + s1 * 8);                                            \
    }
  #define STAGE_B(T2)                                                          \
    {                                                                          \
      int off_ = ((T2) >> 3) * 256 + ((T2) & 7) * 32;                          \
      unsigned short* dst_ = &Bb[(T2) & 3][0];                                 \
      gl_lds16(bB0 + off_, dst_ + s0 * 8);                                     \
      gl_lds16(bB1 + off_, dst_ + s1 * 8);                                     \
    }

  // ---- prologue: tiles 0 and 1 in flight ----
  STAGE_A(0); STAGE_B(0); STAGE_A(1); STAGE_B(1);
  asm volatile("s_waitcnt vmcnt(4)" ::: "memory");   // tile 0 landed; tile 1 in flight
  __builtin_amdgcn_s_barrier();

  for (int t = 0; t < 72; ++t) {
    const unsigned short* Ap = &Ab[t & 3][0];
    const unsigned short* Bp = &Bb[t & 3][0];
    int tp2 = t + 2;
    // ================= phase 0: mf 0..3 =================
    bf16x8 af0[4], bfr[4];
    #pragma unroll
    for (int j = 0; j < 4; ++j)
      af0[j] = __builtin_bit_cast(bf16x8, *(const u16x8*)&Ap[base_af + j * 512]);
    #pragma unroll
    for (int n = 0; n < 4; ++n)
      bfr[n] = __builtin_bit_cast(bf16x8, *(const u16x8*)&Bp[base_bf + n * 512]);
    if (tp2 < 72) STAGE_A(tp2);
    __builtin_amdgcn_s_barrier();
    __builtin_amdgcn_s_setprio(1);
    #pragma unroll
    for (int j = 0; j < 4; ++j)
      #pragma unroll
      for (int n = 0; n < 4; ++n)
        acc[j][n] = __builtin_amdgcn_mfma_f32_16x16x32_bf16(af0[j], bfr[n], acc[j][n], 0, 0, 0);
    __builtin_amdgcn_s_setprio(0);
    __builtin_amdgcn_s_barrier();
    // ================= phase 1: mf 4..7 =================
    bf16x8 af1[4];
    #pragma unroll
    for (int j = 0; j < 4; ++j)
      af1[j] = __builtin_bit_cast(bf16x8, *(const u16x8*)&Ap[base_af + (4 + j) * 512]);
    if (tp2 < 72) STAGE_B(tp2);
    if (t < 69) asm volatile("s_waitcnt vmcnt(4)" ::: "memory");   // t+1 landed, t+2 in flight
    else        asm volatile("s_waitcnt vmcnt(0)" ::: "memory");   // drain tail
    __builtin_amdgcn_s_barrier();
    __builtin_amdgcn_s_setprio(1);
    #pragma unroll
    for (int j = 0; j < 4; ++j)
      #pragma unroll
      for (int n = 0; n < 4; ++n)
        acc[4 + j][n] = __builtin_amdgcn_mfma_f32_16x16x32_bf16(af1[j], bfr[n], acc[4 + j][n], 0, 0, 0);
    __builtin_amdgcn_s_setprio(0);
    __builtin_amdgcn_s_barrier();
  }
  #undef STAGE_A
  #undef STAGE_B

  // ---- epilogue: +bias, group stats (16 groups fully inside this block) ----
  float bias[4], ggv[4], gbv[4];
  #pragma unroll
  for (int nf = 0; nf < 4; ++nf) {
    int co = wc * 64 + nf * 16 + l15;
    bias[nf] = cbias[co]; ggv[nf] = gng[co]; gbv[nf] = gnb[co];
  }
  #pragma unroll
  for (int nf = 0; nf < 4; ++nf) {
    float s1 = 0.f, s2 = 0.f;
    #pragma unroll
    for (int mf = 0; mf < 8; ++mf)
      #pragma unroll
      for (int i = 0; i < 4; ++i) {
        float v = acc[mf][nf][i] + bias[nf];
        acc[mf][nf][i] = v;
        s1 += v; s2 += v * v;
      }
    #pragma unroll
    for (int d = 1; d < 64; d <<= 1) {
      s1 += __shfl_xor(s1, d);
      s2 += __shfl_xor(s2, d);
    }
    if (lane == 0) {
      atomicAdd(&gsum[wc * 4 + nf], s1);
      atomicAdd(&gsq[wc * 4 + nf], s2);
    }
  }
  __syncthreads();
  // ---- normalize + relu + pool ----
  #pragma unroll
  for (int nf = 0; nf < 4; ++nf) {
    int g = wc * 4 + nf;
    float mean = gsum[g] * (1.f / 4096.f);
    float var = gsq[g] * (1.f / 4096.f) - mean * mean;
    float rs = rsqrtf(var + GN_EPS);
    float p = 0.f;
    #pragma unroll
    for (int mf = 0; mf < 8; ++mf)
      #pragma unroll
      for (int i = 0; i < 4; ++i) {
        float v = (acc[mf][nf][i] - mean) * rs * ggv[nf] + gbv[nf];
        p += fmaxf(v, 0.f);
      }
    p += __shfl_xor(p, 16);
    p += __shfl_xor(p, 32);
    if (lane < 16) atomicAdd(&pooled[wc * 64 + nf * 16 + l15], p);
  }
  __syncthreads();
  if (tid < 256)
    enc[mm * 65536 + b * 256 + tid] = pooled[tid] * (1.f / 256.f);
}

// ---------------------------------------------------------------------------
// Projector + LN + l2norm + predictor. One block per row (768 rows).
// ---------------------------------------------------------------------------
__global__ void proj_pred(const float* __restrict__ enc,
                          const float* __restrict__ w1, const float* __restrict__ b1,
                          const float* __restrict__ w2, const float* __restrict__ b2,
                          const float* __restrict__ lng, const float* __restrict__ lnb,
                          const float* __restrict__ pw1, const float* __restrict__ pb1,
                          const float* __restrict__ pw2, const float* __restrict__ pb2,
                          float* __restrict__ proj, float* __restrict__ pred,
                          float* __restrict__ znorm) {
  __shared__ float row[256], h1[256], zz[128], p1[128], red[2];
  int r = blockIdx.x, tid = threadIdx.x;
  row[tid] = enc[r * 256 + tid];
  __syncthreads();
  float a = 0.f;
  for (int k = 0; k < 256; ++k) a += row[k] * w1[k * 256 + tid];
  h1[tid] = fmaxf(a + b1[tid], 0.f);
  __syncthreads();
  if (tid < 128) {
    a = 0.f;
    for (int k = 0; k < 256; ++k) a += h1[k] * w2[k * 128 + tid];
    zz[tid] = a + b2[tid];
  }
  __syncthreads();
  if (tid == 0) {
    float m = 0.f;
    for (int k = 0; k < 128; ++k) m += zz[k];
    m *= (1.f / 128.f);
    float v = 0.f;
    for (int k = 0; k < 128; ++k) { float d = zz[k] - m; v += d * d; }
    red[0] = m;
    red[1] = rsqrtf(v * (1.f / 128.f) + LN_EPS);
  }
  __syncthreads();
  float zval = 0.f;
  if (tid < 128) {
    zval = (zz[tid] - red[0]) * red[1] * lng[tid] + lnb[tid];
    proj[r * 128 + tid] = zval;
  }
  __syncthreads();
  if (tid < 128) zz[tid] = zval;     // zz now holds LN output
  __syncthreads();
  if (tid == 0) {
    float s = 0.f;
    for (int k = 0; k < 128; ++k) s += zz[k] * zz[k];
    red[0] = 1.f / fmaxf(sqrtf(s), COS_EPS_F);
  }
  __syncthreads();
  if (tid < 128) {
    znorm[r * 128 + tid] = zz[tid] * red[0];
    a = 0.f;
    for (int k = 0; k < 128; ++k) a += zz[k] * pw1[k * 128 + tid];
    p1[tid] = fmaxf(a + pb1[tid], 0.f);
  }
  __syncthreads();
  if (tid < 128) {
    a = 0.f;
    for (int k = 0; k < 128; ++k) a += p1[k] * pw2[k * 128 + tid];
    pred[r * 128 + tid] = a + pb2[tid];
  }
}

// ---------------------------------------------------------------------------
// Loss: block = (pair, k). lse(S[k,:]) - S[k,k] per row; partials to ws.
// ---------------------------------------------------------------------------
__global__ void loss_kernel(const float* __restrict__ zn, float* __restrict__ part) {
  __shared__ float zi[128], sv[256], rbuf[256];
  int blk = blockIdx.x;           // p*256 + k
  int p = blk >> 8, k = blk & 255;
  int i = (p == 2) ? 1 : 0;
  int j = (p == 0) ? 1 : 2;
  int tid = threadIdx.x;
  if (tid < 128) zi[tid] = zn[(i * 256 + k) * 128 + tid];
  __syncthreads();
  const float4* zj = (const float4*)&zn[(j * 256 + tid) * 128];
  float s = 0.f;
  #pragma unroll 8
  for (int d = 0; d < 32; ++d) {
    float4 aq = *(const float4*)&zi[d * 4];
    float4 bq = zj[d];
    s += aq.x * bq.x + aq.y * bq.y + aq.z * bq.z + aq.w * bq.w;
  }
  s *= 10.0f;                      // 1/TEMP
  sv[tid] = s;
  rbuf[tid] = s;
  __syncthreads();
  for (int d = 128; d > 0; d >>= 1) {
    if (tid < d) rbuf[tid] = fmaxf(rbuf[tid], rbuf[tid + d]);
    __syncthreads();
  }
  float m = rbuf[0];
  __syncthreads();
  rbuf[tid] = expf(s - m);
  __syncthreads();
  for (int d = 128; d > 0; d >>= 1) {
    if (tid < d) rbuf[tid] += rbuf[tid + d];
    __syncthreads();
  }
  if (tid == 0) part[blk] = m + logf(rbuf[0]) - sv[k];
}

__global__ void finalize_loss(const float* __restrict__ part, float* __restrict__ out) {
  __shared__ float red[256];
  int tid = threadIdx.x;
  float s = 0.f;
  for (int idx = tid; idx < 768; idx += 256) s += part[idx];
  red[tid] = s;
  __syncthreads();
  for (int d = 128; d > 0; d >>= 1) {
    if (tid < d) red[tid] += red[tid + d];
    __syncthreads();
  }
  if (tid == 0) out[0] = red[0] * (1.f / 768.f);
}

// ---------------------------------------------------------------------------
extern "C" void kernel_launch(void* const* d_in, const int* in_sizes, int n_in,
                              void* d_out, int out_size, void* d_ws, size_t ws_size,
                              hipStream_t stream) {
  const float* x[3]  = {(const float*)d_in[0], (const float*)d_in[1], (const float*)d_in[2]};
  const float* cw[3] = {(const float*)d_in[3], (const float*)d_in[7], (const float*)d_in[11]};
  const float* cb[3] = {(const float*)d_in[4], (const float*)d_in[8], (const float*)d_in[12]};
  const float* gg[3] = {(const float*)d_in[5], (const float*)d_in[9], (const float*)d_in[13]};
  const float* gb[3] = {(const float*)d_in[6], (const float*)d_in[10], (const float*)d_in[14]};
  const float* p_w1 = (const float*)d_in[15];
  const float* p_b1 = (const float*)d_in[16];
  const float* p_w2 = (const float*)d_in[17];
  const float* p_b2 = (const float*)d_in[18];
  const float* ln_g = (const float*)d_in[19];
  const float* ln_b = (const float*)d_in[20];
  const float* q_w1 = (const float*)d_in[21];
  const float* q_b1 = (const float*)d_in[22];
  const float* q_w2 = (const float*)d_in[23];
  const float* q_b2 = (const float*)d_in[24];

  float* out = (float*)d_out;
  char* ws = (char*)d_ws;

  const size_t XT_ONE = 33554432;        // bytes per image-set xT
  bool merged = ws_size >= (3 * XT_ONE + 3538944 + 393216 + 3072 + 64);

  size_t xt_total = merged ? 3 * XT_ONE : XT_ONE;
  unsigned short* xT  = (unsigned short*)ws;
  unsigned short* wpk = (unsigned short*)(ws + xt_total);             // 3,538,944 B (3 sets)
  float* znorm = (float*)(ws + xt_total + 3538944);                   //   393,216 B
  float* part  = (float*)(ws + xt_total + 3538944 + 393216);          //     3,072 B
  unsigned short* zb = (unsigned short*)(ws + xt_total + 3538944 + 393216 + 3072);

  float* enc  = out;              // [3][256][256]
  float* proj = out + 196608;     // [3][256][128]
  float* pred = out + 294912;     // [3][256][128]
  float* lossp = out + 393216;    // scalar

  pack_kernel<<<dim3(2304, 3), dim3(256), 0, stream>>>(cw[0], cw[1], cw[2], wpk, zb);

  if (merged) {
    transpose_kernel<<<dim3(6144), dim3(256), 0, stream>>>(x[0], x[1], x[2], xT, 16777216u, 0);
    conv_gn_pool<<<dim3(768), dim3(512), 0, stream>>>(
        xT, 16777216u, wpk, zb, cb[0], cb[1], cb[2], gg[0], gg[1], gg[2],
        gb[0], gb[1], gb[2], enc, 0);
  } else {
    for (int m = 0; m < 3; ++m) {
      transpose_kernel<<<dim3(2048), dim3(256), 0, stream>>>(x[0], x[1], x[2], xT, 0u, m);
      conv_gn_pool<<<dim3(256), dim3(512), 0, stream>>>(
          xT, 0u, wpk, zb, cb[0], cb[1], cb[2], gg[0], gg[1], gg[2],
          gb[0], gb[1], gb[2], enc, m);
    }
  }
  proj_pred<<<dim3(768), dim3(256), 0, stream>>>(enc, p_w1, p_b1, p_w2, p_b2, ln_g, ln_b,
                                                 q_w1, q_b1, q_w2, q_b2, proj, pred, znorm);
  loss_kernel<<<dim3(768), dim3(256), 0, stream>>>(znorm, part);
  finalize_loss<<<dim3(1), dim3(256), 0, stream>>>(part, lossp);
}